// Round 2
// baseline (701.494 us; speedup 1.0000x reference)
//
#include <hip/hip_runtime.h>
#include <hip/hip_bf16.h>
#include <stdint.h>

// ---------------------------------------------------------------------------
// 2-layer GAT (inference) on MI355X, dtype-adaptive.
//   Runtime-detected: float inputs f32 vs bf16; edge_index int32 vs int64.
//   Intermediates (h1, x2, h2) always bf16 (our choice). Output follows the
//   detected float dtype (bf16 dataset => bf16 out, f32 => f32 out).
//   CSR built per launch; no f32 atomics anywhere.
// ---------------------------------------------------------------------------

#define BM 64
#define BN 64
#define BK 16

__device__ __forceinline__ float bf2f(__hip_bfloat16 v) { return __bfloat162float(v); }

template <bool BF>
__device__ __forceinline__ float loadF(const void* p, size_t i) {
  if (BF) return bf2f(((const __hip_bfloat16*)p)[i]);
  return ((const float*)p)[i];
}
template <bool BF>
__device__ __forceinline__ void storeF(void* p, size_t i, float v) {
  if (BF) ((__hip_bfloat16*)p)[i] = __float2bfloat16(v);
  else    ((float*)p)[i] = v;
}
template <bool I64>
__device__ __forceinline__ int loadI(const void* p, size_t i) {
  if (I64) return (int)((const long long*)p)[i];
  return ((const int*)p)[i];
}

// ----------------- dtype detection (1 thread) ------------------------------
// flags[0] = 1 if float inputs are bf16, 0 if f32.
// flags[1] = 1 if edge_index is int64, 0 if int32.
__global__ void detect_kernel(const uint32_t* __restrict__ xbits,
                              const uint32_t* __restrict__ eibits,
                              int* __restrict__ flags) {
  if (threadIdx.x != 0 || blockIdx.x != 0) return;
  int plausible = 0;
  for (int i = 0; i < 64; i++) {
    uint32_t u = xbits[i];
    uint32_t e = (u >> 23) & 0xffu;
    // x ~ N(0,1) as f32: exponent ~[90,130] (or exact zero). bf16-pair
    // misread as f32: exponent >= ~192. Clean separation at 160.
    if ((e < 160u && e > 90u) || (u & 0x7fffffffu) == 0u) plausible++;
  }
  flags[0] = (plausible < 32) ? 1 : 0;
  int allz = 1;
  for (int i = 0; i < 64; i++)
    if (eibits[2 * i + 1] != 0u) allz = 0;
  flags[1] = allz;
}

// ----------------- GEMM: C[M,N] = A[M,K] @ B[K,N], f32 acc, bf16 C ---------
template <bool ABF, bool BBF>
__device__ __forceinline__ void gemm_body(const void* __restrict__ A,
                                          const void* __restrict__ B,
                                          __hip_bfloat16* __restrict__ C,
                                          int M, int K, int N,
                                          float (*As)[BM + 1], float (*Bs)[BN + 1]) {
  const int tx = threadIdx.x & 15;
  const int ty = threadIdx.x >> 4;
  const int m0 = blockIdx.x * BM;
  const int n0 = blockIdx.y * BN;
  float acc[4][4] = {};
  for (int k0 = 0; k0 < K; k0 += BK) {
    for (int j = 0; j < 4; j++) {
      int i = threadIdx.x + 256 * j;
      int r = i >> 4, c = i & 15;
      int gm = m0 + r;
      float v = 0.f;
      if (gm < M) v = loadF<ABF>(A, (size_t)gm * K + k0 + c);
      As[c][r] = v;
    }
    for (int j = 0; j < 4; j++) {
      int i = threadIdx.x + 256 * j;
      int r = i >> 6, c = i & 63;
      Bs[r][c] = loadF<BBF>(B, (size_t)(k0 + r) * N + n0 + c);
    }
    __syncthreads();
#pragma unroll
    for (int kk = 0; kk < BK; kk++) {
      float a[4], b[4];
#pragma unroll
      for (int r = 0; r < 4; r++) a[r] = As[kk][ty * 4 + r];
#pragma unroll
      for (int c = 0; c < 4; c++) b[c] = Bs[kk][tx * 4 + c];
#pragma unroll
      for (int r = 0; r < 4; r++)
#pragma unroll
        for (int c = 0; c < 4; c++) acc[r][c] += a[r] * b[c];
    }
    __syncthreads();
  }
  for (int r = 0; r < 4; r++) {
    int gm = m0 + ty * 4 + r;
    if (gm >= M) continue;
    for (int c = 0; c < 4; c++)
      C[(size_t)gm * N + n0 + tx * 4 + c] = __float2bfloat16(acc[r][c]);
  }
}

__global__ __launch_bounds__(256) void gemm_any(const void* __restrict__ A,
                                                const void* __restrict__ B,
                                                __hip_bfloat16* __restrict__ C,
                                                int M, int K, int N,
                                                const int* __restrict__ flags,
                                                int forceAbf) {
  __shared__ float As[BK][BM + 1];
  __shared__ float Bs[BK][BN + 1];
  const bool f = flags[0] != 0;
  if (forceAbf || f) {
    if (f) gemm_body<true, true>(A, B, C, M, K, N, As, Bs);
    else   gemm_body<true, false>(A, B, C, M, K, N, As, Bs);
  } else {
    gemm_body<false, false>(A, B, C, M, K, N, As, Bs);
  }
}

// ----------------- per-(node,head) attention dots --------------------------
__global__ void att_dot(const __hip_bfloat16* __restrict__ hx,
                        const void* __restrict__ att_s, const void* __restrict__ att_d,
                        float* __restrict__ as_o, float* __restrict__ ad_o,
                        int H, const int* __restrict__ flags) {
  const int n = blockIdx.x;
  const int hh = threadIdx.x >> 6;
  const int l = threadIdx.x & 63;
  const bool f = flags[0] != 0;
  float v = bf2f(hx[((size_t)n * H + hh) * 64 + l]);
  float ws_ = f ? loadF<true>(att_s, hh * 64 + l) : loadF<false>(att_s, hh * 64 + l);
  float wd_ = f ? loadF<true>(att_d, hh * 64 + l) : loadF<false>(att_d, hh * 64 + l);
  float ps = v * ws_;
  float pd = v * wd_;
#pragma unroll
  for (int o = 32; o > 0; o >>= 1) {
    ps += __shfl_xor(ps, o);
    pd += __shfl_xor(pd, o);
  }
  if (l == 0) {
    as_o[n * H + hh] = ps;
    ad_o[n * H + hh] = pd;
  }
}

// ----------------- CSR build ------------------------------------------------
__global__ void hist_kernel(const void* __restrict__ ei, int E,
                            int* __restrict__ deg, const int* __restrict__ flags) {
  int e = blockIdx.x * blockDim.x + threadIdx.x;
  if (e >= E) return;
  int d = flags[1] ? loadI<true>(ei, (size_t)E + e) : loadI<false>(ei, (size_t)E + e);
  atomicAdd(&deg[d], 1);
}

__global__ __launch_bounds__(1024) void scan_ex(const int* __restrict__ deg,
                                                int* __restrict__ row_start, int n) {
  __shared__ int buf[1024];
  __shared__ int carry;
  const int tid = threadIdx.x;
  if (tid == 0) { carry = 0; row_start[0] = 0; }
  __syncthreads();
  for (int base = 0; base < n; base += 1024) {
    int i = base + tid;
    buf[tid] = (i < n) ? deg[i] : 0;
    __syncthreads();
    for (int off = 1; off < 1024; off <<= 1) {
      int t = (tid >= off) ? buf[tid - off] : 0;
      __syncthreads();
      buf[tid] += t;
      __syncthreads();
    }
    int c = carry;
    if (i < n) row_start[i + 1] = c + buf[tid];
    __syncthreads();
    if (tid == 0) carry = c + buf[1023];
    __syncthreads();
  }
}

__global__ void scatter_edges(const void* __restrict__ ei, int E,
                              const int* __restrict__ row_start,
                              int* __restrict__ cursor, int* __restrict__ col_src,
                              const int* __restrict__ flags) {
  int e = blockIdx.x * blockDim.x + threadIdx.x;
  if (e >= E) return;
  int s, d;
  if (flags[1]) { s = loadI<true>(ei, e);  d = loadI<true>(ei, (size_t)E + e); }
  else          { s = loadI<false>(ei, e); d = loadI<false>(ei, (size_t)E + e); }
  int pos = atomicAdd(&cursor[d], 1);
  col_src[row_start[d] + pos] = s;
}

// ----------------- per-dst softmax-weighted aggregation --------------------
template <bool APPLY_ELU>
__global__ void aggregate(const __hip_bfloat16* __restrict__ h_in,
                          const float* __restrict__ as_, const float* __restrict__ ad_,
                          const void* __restrict__ bias,
                          const int* __restrict__ row_start, const int* __restrict__ col_src,
                          void* __restrict__ out, int H,
                          const int* __restrict__ flags, int forceOutBf) {
  const int dst = blockIdx.x;
  const int hh = threadIdx.x >> 6;
  const int l = threadIdx.x & 63;
  const bool f = flags[0] != 0;
  const int rs = row_start[dst];
  const int deg = row_start[dst + 1] - rs;
  const float adv = ad_[dst * H + hh];
  float e_self = as_[dst * H + hh] + adv;
  e_self = e_self > 0.f ? e_self : 0.2f * e_self;

  // pass 1: max over incoming edges (lanes parallel)
  float m = e_self;
  for (int base = 0; base < deg; base += 64) {
    int i = base + l;
    if (i < deg) {
      int sn = col_src[rs + i];
      float v = as_[sn * H + hh] + adv;
      v = v > 0.f ? v : 0.2f * v;
      m = fmaxf(m, v);
    }
  }
#pragma unroll
  for (int o = 32; o > 0; o >>= 1) m = fmaxf(m, __shfl_xor(m, o));

  // pass 2: sum of exp
  float p = 0.f;
  for (int base = 0; base < deg; base += 64) {
    int i = base + l;
    if (i < deg) {
      int sn = col_src[rs + i];
      float v = as_[sn * H + hh] + adv;
      v = v > 0.f ? v : 0.2f * v;
      p += __expf(v - m);
    }
  }
#pragma unroll
  for (int o = 32; o > 0; o >>= 1) p += __shfl_xor(p, o);
  const float w_self = __expf(e_self - m);
  const float inv = 1.0f / (p + w_self + 1e-16f);

  // pass 3: weighted channel sum (lane = channel, serial over edges)
  float acc = w_self * bf2f(h_in[((size_t)dst * H + hh) * 64 + l]);
  for (int e = 0; e < deg; e++) {
    int sn = col_src[rs + e];
    float v = as_[sn * H + hh] + adv;
    v = v > 0.f ? v : 0.2f * v;
    acc += __expf(v - m) * bf2f(h_in[((size_t)sn * H + hh) * 64 + l]);
  }
  float bv = f ? loadF<true>(bias, hh * 64 + l) : loadF<false>(bias, hh * 64 + l);
  float o = acc * inv + bv;
  if (APPLY_ELU) o = o > 0.f ? o : __expf(o) - 1.0f;
  size_t oi = ((size_t)dst * H + hh) * 64 + l;
  if (forceOutBf || f) storeF<true>(out, oi, o);
  else                 storeF<false>(out, oi, o);
}

// ---------------------------------------------------------------------------
extern "C" void kernel_launch(void* const* d_in, const int* in_sizes, int n_in,
                              void* d_out, int out_size, void* d_ws, size_t ws_size,
                              hipStream_t stream) {
  const void* x    = d_in[0];
  const void* ei   = d_in[1];
  const void* W1   = d_in[2];
  const void* as1w = d_in[3];
  const void* ad1w = d_in[4];
  const void* b1   = d_in[5];
  const void* W2   = d_in[6];
  const void* as2w = d_in[7];
  const void* ad2w = d_in[8];
  const void* b2   = d_in[9];

  const int N  = out_size / 64;      // 50000
  const int F  = in_sizes[0] / N;    // 128
  const int E  = in_sizes[1] / 2;    // 800000
  const int H1 = in_sizes[3] / 64;   // 4
  const int D1 = H1 * 64;            // 256
  const int H2 = in_sizes[7] / 64;   // 1
  const int D2 = H2 * 64;            // 64

  size_t off = 0;
  auto alloc = [&](size_t bytes) -> void* {
    void* p = (char*)d_ws + off;
    off += (bytes + 255) & ~(size_t)255;
    return p;
  };
  int* flags = (int*)alloc(2 * sizeof(int));
  __hip_bfloat16* h1 = (__hip_bfloat16*)alloc((size_t)N * D1 * 2);
  __hip_bfloat16* x2 = (__hip_bfloat16*)alloc((size_t)N * D1 * 2);
  __hip_bfloat16* h2 = h1;  // h1 dead after layer-1 aggregate; reuse
  float* as1 = (float*)alloc((size_t)N * H1 * 4);
  float* ad1 = (float*)alloc((size_t)N * H1 * 4);
  float* as2 = (float*)alloc((size_t)N * H2 * 4);
  float* ad2 = (float*)alloc((size_t)N * H2 * 4);
  int* degcur = (int*)alloc((size_t)2 * N * 4);  // deg | cursor
  int* deg = degcur;
  int* cursor = degcur + N;
  int* row_start = (int*)alloc((size_t)(N + 1) * 4);
  int* col_src = (int*)alloc((size_t)E * 4);
  (void)ws_size; (void)n_in;

  // ---- dtype detection + CSR build
  detect_kernel<<<1, 64, 0, stream>>>((const uint32_t*)x, (const uint32_t*)ei, flags);
  hipMemsetAsync(degcur, 0, (size_t)2 * N * 4, stream);
  hist_kernel<<<(E + 255) / 256, 256, 0, stream>>>(ei, E, deg, flags);
  scan_ex<<<1, 1024, 0, stream>>>(deg, row_start, N);
  scatter_edges<<<(E + 255) / 256, 256, 0, stream>>>(ei, E, row_start, cursor, col_src, flags);

  // ---- layer 1
  gemm_any<<<dim3((N + BM - 1) / BM, D1 / BN), 256, 0, stream>>>(x, W1, h1, N, F, D1, flags, 0);
  att_dot<<<N, H1 * 64, 0, stream>>>(h1, as1w, ad1w, as1, ad1, H1, flags);
  aggregate<true><<<N, H1 * 64, 0, stream>>>(h1, as1, ad1, b1, row_start, col_src,
                                             x2, H1, flags, 1);

  // ---- layer 2
  gemm_any<<<dim3((N + BM - 1) / BM, D2 / BN), 256, 0, stream>>>(x2, W2, h2, N, D1, D2, flags, 1);
  att_dot<<<N, H2 * 64, 0, stream>>>(h2, as2w, ad2w, as2, ad2, H2, flags);
  aggregate<false><<<N, H2 * 64, 0, stream>>>(h2, as2, ad2, b2, row_start, col_src,
                                              d_out, H2, flags, 0);
}

// Round 4
// 602.725 us; speedup vs baseline: 1.1639x; 1.1639x over previous
//
#include <hip/hip_runtime.h>
#include <hip/hip_bf16.h>
#include <stdint.h>

// ---------------------------------------------------------------------------
// 2-layer GAT (inference) on MI355X, dtype-adaptive.
//   Base = round-2 PASSING kernel. Only change: aggregate pass 3 stages
//   (col_src, softmax weight) into LDS lane-parallel, then runs the serial
//   accumulation from LDS -> h_in row gathers become independent loads (MLP)
//   instead of a dependent-load chain. Summation order identical to round 2.
// ---------------------------------------------------------------------------

#define BM 64
#define BN 64
#define BK 16

__device__ __forceinline__ float bf2f(__hip_bfloat16 v) { return __bfloat162float(v); }

template <bool BF>
__device__ __forceinline__ float loadF(const void* p, size_t i) {
  if (BF) return bf2f(((const __hip_bfloat16*)p)[i]);
  return ((const float*)p)[i];
}
template <bool BF>
__device__ __forceinline__ void storeF(void* p, size_t i, float v) {
  if (BF) ((__hip_bfloat16*)p)[i] = __float2bfloat16(v);
  else    ((float*)p)[i] = v;
}
template <bool I64>
__device__ __forceinline__ int loadI(const void* p, size_t i) {
  if (I64) return (int)((const long long*)p)[i];
  return ((const int*)p)[i];
}
__device__ __forceinline__ float lrelu(float v) { return v > 0.f ? v : 0.2f * v; }

// ----------------- dtype detection (1 thread) ------------------------------
// flags[0] = 1 if float inputs are bf16, 0 if f32.
// flags[1] = 1 if edge_index is int64, 0 if int32.
__global__ void detect_kernel(const uint32_t* __restrict__ xbits,
                              const uint32_t* __restrict__ eibits,
                              int* __restrict__ flags) {
  if (threadIdx.x != 0 || blockIdx.x != 0) return;
  int plausible = 0;
  for (int i = 0; i < 64; i++) {
    uint32_t u = xbits[i];
    uint32_t e = (u >> 23) & 0xffu;
    if ((e < 160u && e > 90u) || (u & 0x7fffffffu) == 0u) plausible++;
  }
  flags[0] = (plausible < 32) ? 1 : 0;
  int allz = 1;
  for (int i = 0; i < 64; i++)
    if (eibits[2 * i + 1] != 0u) allz = 0;
  flags[1] = allz;
}

// ----------------- GEMM: C[M,N] = A[M,K] @ B[K,N], f32 acc, bf16 C ---------
template <bool ABF, bool BBF>
__device__ __forceinline__ void gemm_body(const void* __restrict__ A,
                                          const void* __restrict__ B,
                                          __hip_bfloat16* __restrict__ C,
                                          int M, int K, int N,
                                          float (*As)[BM + 1], float (*Bs)[BN + 1]) {
  const int tx = threadIdx.x & 15;
  const int ty = threadIdx.x >> 4;
  const int m0 = blockIdx.x * BM;
  const int n0 = blockIdx.y * BN;
  float acc[4][4] = {};
  for (int k0 = 0; k0 < K; k0 += BK) {
    for (int j = 0; j < 4; j++) {
      int i = threadIdx.x + 256 * j;
      int r = i >> 4, c = i & 15;
      int gm = m0 + r;
      float v = 0.f;
      if (gm < M) v = loadF<ABF>(A, (size_t)gm * K + k0 + c);
      As[c][r] = v;
    }
    for (int j = 0; j < 4; j++) {
      int i = threadIdx.x + 256 * j;
      int r = i >> 6, c = i & 63;
      Bs[r][c] = loadF<BBF>(B, (size_t)(k0 + r) * N + n0 + c);
    }
    __syncthreads();
#pragma unroll
    for (int kk = 0; kk < BK; kk++) {
      float a[4], b[4];
#pragma unroll
      for (int r = 0; r < 4; r++) a[r] = As[kk][ty * 4 + r];
#pragma unroll
      for (int c = 0; c < 4; c++) b[c] = Bs[kk][tx * 4 + c];
#pragma unroll
      for (int r = 0; r < 4; r++)
#pragma unroll
        for (int c = 0; c < 4; c++) acc[r][c] += a[r] * b[c];
    }
    __syncthreads();
  }
  for (int r = 0; r < 4; r++) {
    int gm = m0 + ty * 4 + r;
    if (gm >= M) continue;
    for (int c = 0; c < 4; c++)
      C[(size_t)gm * N + n0 + tx * 4 + c] = __float2bfloat16(acc[r][c]);
  }
}

__global__ __launch_bounds__(256) void gemm_any(const void* __restrict__ A,
                                                const void* __restrict__ B,
                                                __hip_bfloat16* __restrict__ C,
                                                int M, int K, int N,
                                                const int* __restrict__ flags,
                                                int forceAbf) {
  __shared__ float As[BK][BM + 1];
  __shared__ float Bs[BK][BN + 1];
  const bool f = flags[0] != 0;
  if (forceAbf || f) {
    if (f) gemm_body<true, true>(A, B, C, M, K, N, As, Bs);
    else   gemm_body<true, false>(A, B, C, M, K, N, As, Bs);
  } else {
    gemm_body<false, false>(A, B, C, M, K, N, As, Bs);
  }
}

// ----------------- per-(node,head) attention dots --------------------------
__global__ void att_dot(const __hip_bfloat16* __restrict__ hx,
                        const void* __restrict__ att_s, const void* __restrict__ att_d,
                        float* __restrict__ as_o, float* __restrict__ ad_o,
                        int H, const int* __restrict__ flags) {
  const int n = blockIdx.x;
  const int hh = threadIdx.x >> 6;
  const int l = threadIdx.x & 63;
  const bool f = flags[0] != 0;
  float v = bf2f(hx[((size_t)n * H + hh) * 64 + l]);
  float ws_ = f ? loadF<true>(att_s, hh * 64 + l) : loadF<false>(att_s, hh * 64 + l);
  float wd_ = f ? loadF<true>(att_d, hh * 64 + l) : loadF<false>(att_d, hh * 64 + l);
  float ps = v * ws_;
  float pd = v * wd_;
#pragma unroll
  for (int o = 32; o > 0; o >>= 1) {
    ps += __shfl_xor(ps, o);
    pd += __shfl_xor(pd, o);
  }
  if (l == 0) {
    as_o[n * H + hh] = ps;
    ad_o[n * H + hh] = pd;
  }
}

// ----------------- CSR build ------------------------------------------------
__global__ void hist_kernel(const void* __restrict__ ei, int E,
                            int* __restrict__ deg, const int* __restrict__ flags) {
  int e = blockIdx.x * blockDim.x + threadIdx.x;
  if (e >= E) return;
  int d = flags[1] ? loadI<true>(ei, (size_t)E + e) : loadI<false>(ei, (size_t)E + e);
  atomicAdd(&deg[d], 1);
}

__global__ __launch_bounds__(1024) void scan_ex(const int* __restrict__ deg,
                                                int* __restrict__ row_start, int n) {
  __shared__ int buf[1024];
  __shared__ int carry;
  const int tid = threadIdx.x;
  if (tid == 0) { carry = 0; row_start[0] = 0; }
  __syncthreads();
  for (int base = 0; base < n; base += 1024) {
    int i = base + tid;
    buf[tid] = (i < n) ? deg[i] : 0;
    __syncthreads();
    for (int off = 1; off < 1024; off <<= 1) {
      int t = (tid >= off) ? buf[tid - off] : 0;
      __syncthreads();
      buf[tid] += t;
      __syncthreads();
    }
    int c = carry;
    if (i < n) row_start[i + 1] = c + buf[tid];
    __syncthreads();
    if (tid == 0) carry = c + buf[1023];
    __syncthreads();
  }
}

__global__ void scatter_edges(const void* __restrict__ ei, int E,
                              const int* __restrict__ row_start,
                              int* __restrict__ cursor, int* __restrict__ col_src,
                              const int* __restrict__ flags) {
  int e = blockIdx.x * blockDim.x + threadIdx.x;
  if (e >= E) return;
  int s, d;
  if (flags[1]) { s = loadI<true>(ei, e);  d = loadI<true>(ei, (size_t)E + e); }
  else          { s = loadI<false>(ei, e); d = loadI<false>(ei, (size_t)E + e); }
  int pos = atomicAdd(&cursor[d], 1);
  col_src[row_start[d] + pos] = s;
}

// ----------------- per-dst softmax-weighted aggregation --------------------
// Identical math/order to the round-2 passing version; pass 3 now stages
// (sn, weight) into LDS lane-parallel, then accumulates serially from LDS
// so the h_in row gathers are independent (memory-level parallelism).
template <bool APPLY_ELU>
__global__ void aggregate(const __hip_bfloat16* __restrict__ h_in,
                          const float* __restrict__ as_, const float* __restrict__ ad_,
                          const void* __restrict__ bias,
                          const int* __restrict__ row_start, const int* __restrict__ col_src,
                          void* __restrict__ out, int H,
                          const int* __restrict__ flags, int forceOutBf) {
  __shared__ float w_lds[4][64];
  __shared__ int   s_lds[4][64];
  const int dst = blockIdx.x;
  const int hh = threadIdx.x >> 6;
  const int l = threadIdx.x & 63;
  const bool f = flags[0] != 0;
  const int rs = row_start[dst];
  const int deg = row_start[dst + 1] - rs;
  const float adv = ad_[dst * H + hh];
  float e_self = as_[dst * H + hh] + adv;
  e_self = lrelu(e_self);

  // pass 1: max over incoming edges (lanes parallel)
  float m = e_self;
  for (int base = 0; base < deg; base += 64) {
    int i = base + l;
    if (i < deg) {
      int sn = col_src[rs + i];
      m = fmaxf(m, lrelu(as_[sn * H + hh] + adv));
    }
  }
#pragma unroll
  for (int o = 32; o > 0; o >>= 1) m = fmaxf(m, __shfl_xor(m, o));

  // pass 2: sum of exp
  float p = 0.f;
  for (int base = 0; base < deg; base += 64) {
    int i = base + l;
    if (i < deg) {
      int sn = col_src[rs + i];
      p += __expf(lrelu(as_[sn * H + hh] + adv) - m);
    }
  }
#pragma unroll
  for (int o = 32; o > 0; o >>= 1) p += __shfl_xor(p, o);
  const float w_self = __expf(e_self - m);
  const float inv = 1.0f / (p + w_self + 1e-16f);

  // pass 3: weighted channel sum (lane = channel), LDS-staged weights.
  float acc = w_self * bf2f(h_in[((size_t)dst * H + hh) * 64 + l]);
  for (int base = 0; base < deg; base += 64) {
    int i = base + l;
    if (i < deg) {
      int sn = col_src[rs + i];
      s_lds[hh][l] = sn;
      w_lds[hh][l] = __expf(lrelu(as_[sn * H + hh] + adv) - m);
    }
    __syncthreads();
    const int cnt = min(64, deg - base);
#pragma unroll 4
    for (int e = 0; e < cnt; e++) {
      int sn = s_lds[hh][e];
      float w = w_lds[hh][e];
      acc += w * bf2f(h_in[((size_t)sn * H + hh) * 64 + l]);
    }
    __syncthreads();
  }

  float bv = f ? loadF<true>(bias, hh * 64 + l) : loadF<false>(bias, hh * 64 + l);
  float o = acc * inv + bv;
  if (APPLY_ELU) o = o > 0.f ? o : __expf(o) - 1.0f;
  size_t oi = ((size_t)dst * H + hh) * 64 + l;
  if (forceOutBf || f) storeF<true>(out, oi, o);
  else                 storeF<false>(out, oi, o);
}

// ---------------------------------------------------------------------------
extern "C" void kernel_launch(void* const* d_in, const int* in_sizes, int n_in,
                              void* d_out, int out_size, void* d_ws, size_t ws_size,
                              hipStream_t stream) {
  const void* x    = d_in[0];
  const void* ei   = d_in[1];
  const void* W1   = d_in[2];
  const void* as1w = d_in[3];
  const void* ad1w = d_in[4];
  const void* b1   = d_in[5];
  const void* W2   = d_in[6];
  const void* as2w = d_in[7];
  const void* ad2w = d_in[8];
  const void* b2   = d_in[9];

  const int N  = out_size / 64;      // 50000
  const int F  = in_sizes[0] / N;    // 128
  const int E  = in_sizes[1] / 2;    // 800000
  const int H1 = in_sizes[3] / 64;   // 4
  const int D1 = H1 * 64;            // 256
  const int H2 = in_sizes[7] / 64;   // 1
  const int D2 = H2 * 64;            // 64

  size_t off = 0;
  auto alloc = [&](size_t bytes) -> void* {
    void* p = (char*)d_ws + off;
    off += (bytes + 255) & ~(size_t)255;
    return p;
  };
  int* flags = (int*)alloc(2 * sizeof(int));
  __hip_bfloat16* h1 = (__hip_bfloat16*)alloc((size_t)N * D1 * 2);
  __hip_bfloat16* x2 = (__hip_bfloat16*)alloc((size_t)N * D1 * 2);
  __hip_bfloat16* h2 = h1;  // h1 dead after layer-1 aggregate; reuse
  float* as1 = (float*)alloc((size_t)N * H1 * 4);
  float* ad1 = (float*)alloc((size_t)N * H1 * 4);
  float* as2 = (float*)alloc((size_t)N * H2 * 4);
  float* ad2 = (float*)alloc((size_t)N * H2 * 4);
  int* degcur = (int*)alloc((size_t)2 * N * 4);  // deg | cursor
  int* deg = degcur;
  int* cursor = degcur + N;
  int* row_start = (int*)alloc((size_t)(N + 1) * 4);
  int* col_src = (int*)alloc((size_t)E * 4);
  (void)ws_size; (void)n_in;

  // ---- dtype detection + CSR build
  detect_kernel<<<1, 64, 0, stream>>>((const uint32_t*)x, (const uint32_t*)ei, flags);
  hipMemsetAsync(degcur, 0, (size_t)2 * N * 4, stream);
  hist_kernel<<<(E + 255) / 256, 256, 0, stream>>>(ei, E, deg, flags);
  scan_ex<<<1, 1024, 0, stream>>>(deg, row_start, N);
  scatter_edges<<<(E + 255) / 256, 256, 0, stream>>>(ei, E, row_start, cursor, col_src, flags);

  // ---- layer 1
  gemm_any<<<dim3((N + BM - 1) / BM, D1 / BN), 256, 0, stream>>>(x, W1, h1, N, F, D1, flags, 0);
  att_dot<<<N, H1 * 64, 0, stream>>>(h1, as1w, ad1w, as1, ad1, H1, flags);
  aggregate<true><<<N, H1 * 64, 0, stream>>>(h1, as1, ad1, b1, row_start, col_src,
                                             x2, H1, flags, 1);

  // ---- layer 2
  gemm_any<<<dim3((N + BM - 1) / BM, D2 / BN), 256, 0, stream>>>(x2, W2, h2, N, D1, D2, flags, 1);
  att_dot<<<N, H2 * 64, 0, stream>>>(h2, as2w, ad2w, as2, ad2, H2, flags);
  aggregate<false><<<N, H2 * 64, 0, stream>>>(h2, as2, ad2, b2, row_start, col_src,
                                              d_out, N == 0 ? 1 : H2, flags, 0);
}

// Round 5
// 511.394 us; speedup vs baseline: 1.3717x; 1.1786x over previous
//
#include <hip/hip_runtime.h>
#include <hip/hip_bf16.h>
#include <stdint.h>

// ---------------------------------------------------------------------------
// 2-layer GAT (inference) on MI355X, dtype-adaptive.
// Round-5 changes vs round-4 (passing, 602 us):
//  1. aggregate_v: pass-2 (sum of exp) fused into pass-3's staging loop
//     (bit-identical accumulation order), and the serial gather loop now runs
//     4 edges in flight (wave = 4 edge-slots x 16 channel-lanes, ushort4
//     loads) -> 4x memory-level parallelism in the critical loop.
//  2. Serial single-block scan replaced by a 3-kernel ordered scan producing
//     byte-identical row_start (deterministic, parallel).
// Everything else identical to round 4.
// ---------------------------------------------------------------------------

#define BM 64
#define BN 64
#define BK 16

__device__ __forceinline__ float bf2f(__hip_bfloat16 v) { return __bfloat162float(v); }

__device__ __forceinline__ float bfbits2f(unsigned short s) {
  union { uint32_t u; float f; } v; v.u = ((uint32_t)s) << 16; return v.f;
}

template <bool BF>
__device__ __forceinline__ float loadF(const void* p, size_t i) {
  if (BF) return bf2f(((const __hip_bfloat16*)p)[i]);
  return ((const float*)p)[i];
}
template <bool BF>
__device__ __forceinline__ void storeF(void* p, size_t i, float v) {
  if (BF) ((__hip_bfloat16*)p)[i] = __float2bfloat16(v);
  else    ((float*)p)[i] = v;
}
template <bool I64>
__device__ __forceinline__ int loadI(const void* p, size_t i) {
  if (I64) return (int)((const long long*)p)[i];
  return ((const int*)p)[i];
}
__device__ __forceinline__ float lrelu(float v) { return v > 0.f ? v : 0.2f * v; }

// ----------------- dtype detection (1 thread) ------------------------------
__global__ void detect_kernel(const uint32_t* __restrict__ xbits,
                              const uint32_t* __restrict__ eibits,
                              int* __restrict__ flags) {
  if (threadIdx.x != 0 || blockIdx.x != 0) return;
  int plausible = 0;
  for (int i = 0; i < 64; i++) {
    uint32_t u = xbits[i];
    uint32_t e = (u >> 23) & 0xffu;
    if ((e < 160u && e > 90u) || (u & 0x7fffffffu) == 0u) plausible++;
  }
  flags[0] = (plausible < 32) ? 1 : 0;  // 1 = floats are bf16
  int allz = 1;
  for (int i = 0; i < 64; i++)
    if (eibits[2 * i + 1] != 0u) allz = 0;
  flags[1] = allz;                      // 1 = edge_index is int64
}

// ----------------- GEMM (unchanged from round 4) ---------------------------
template <bool ABF, bool BBF>
__device__ __forceinline__ void gemm_body(const void* __restrict__ A,
                                          const void* __restrict__ B,
                                          __hip_bfloat16* __restrict__ C,
                                          int M, int K, int N,
                                          float (*As)[BM + 1], float (*Bs)[BN + 1]) {
  const int tx = threadIdx.x & 15;
  const int ty = threadIdx.x >> 4;
  const int m0 = blockIdx.x * BM;
  const int n0 = blockIdx.y * BN;
  float acc[4][4] = {};
  for (int k0 = 0; k0 < K; k0 += BK) {
    for (int j = 0; j < 4; j++) {
      int i = threadIdx.x + 256 * j;
      int r = i >> 4, c = i & 15;
      int gm = m0 + r;
      float v = 0.f;
      if (gm < M) v = loadF<ABF>(A, (size_t)gm * K + k0 + c);
      As[c][r] = v;
    }
    for (int j = 0; j < 4; j++) {
      int i = threadIdx.x + 256 * j;
      int r = i >> 6, c = i & 63;
      Bs[r][c] = loadF<BBF>(B, (size_t)(k0 + r) * N + n0 + c);
    }
    __syncthreads();
#pragma unroll
    for (int kk = 0; kk < BK; kk++) {
      float a[4], b[4];
#pragma unroll
      for (int r = 0; r < 4; r++) a[r] = As[kk][ty * 4 + r];
#pragma unroll
      for (int c = 0; c < 4; c++) b[c] = Bs[kk][tx * 4 + c];
#pragma unroll
      for (int r = 0; r < 4; r++)
#pragma unroll
        for (int c = 0; c < 4; c++) acc[r][c] += a[r] * b[c];
    }
    __syncthreads();
  }
  for (int r = 0; r < 4; r++) {
    int gm = m0 + ty * 4 + r;
    if (gm >= M) continue;
    for (int c = 0; c < 4; c++)
      C[(size_t)gm * N + n0 + tx * 4 + c] = __float2bfloat16(acc[r][c]);
  }
}

__global__ __launch_bounds__(256) void gemm_any(const void* __restrict__ A,
                                                const void* __restrict__ B,
                                                __hip_bfloat16* __restrict__ C,
                                                int M, int K, int N,
                                                const int* __restrict__ flags,
                                                int forceAbf) {
  __shared__ float As[BK][BM + 1];
  __shared__ float Bs[BK][BN + 1];
  const bool f = flags[0] != 0;
  if (forceAbf || f) {
    if (f) gemm_body<true, true>(A, B, C, M, K, N, As, Bs);
    else   gemm_body<true, false>(A, B, C, M, K, N, As, Bs);
  } else {
    gemm_body<false, false>(A, B, C, M, K, N, As, Bs);
  }
}

// ----------------- per-(node,head) attention dots --------------------------
__global__ void att_dot(const __hip_bfloat16* __restrict__ hx,
                        const void* __restrict__ att_s, const void* __restrict__ att_d,
                        float* __restrict__ as_o, float* __restrict__ ad_o,
                        int H, const int* __restrict__ flags) {
  const int n = blockIdx.x;
  const int hh = threadIdx.x >> 6;
  const int l = threadIdx.x & 63;
  const bool f = flags[0] != 0;
  float v = bf2f(hx[((size_t)n * H + hh) * 64 + l]);
  float ws_ = f ? loadF<true>(att_s, hh * 64 + l) : loadF<false>(att_s, hh * 64 + l);
  float wd_ = f ? loadF<true>(att_d, hh * 64 + l) : loadF<false>(att_d, hh * 64 + l);
  float ps = v * ws_;
  float pd = v * wd_;
#pragma unroll
  for (int o = 32; o > 0; o >>= 1) {
    ps += __shfl_xor(ps, o);
    pd += __shfl_xor(pd, o);
  }
  if (l == 0) {
    as_o[n * H + hh] = ps;
    ad_o[n * H + hh] = pd;
  }
}

// ----------------- CSR build ------------------------------------------------
__global__ void hist_kernel(const void* __restrict__ ei, int E,
                            int* __restrict__ deg, const int* __restrict__ flags) {
  int e = blockIdx.x * blockDim.x + threadIdx.x;
  if (e >= E) return;
  int d = flags[1] ? loadI<true>(ei, (size_t)E + e) : loadI<false>(ei, (size_t)E + e);
  atomicAdd(&deg[d], 1);
}

// ordered parallel scan, 3 kernels; produces row_start identical to the old
// serial scan_ex (row_start[0]=0, row_start[i+1]=prefix through i).
__global__ __launch_bounds__(256) void scan_block_sums(const int* __restrict__ deg,
                                                       int* __restrict__ bsum, int n) {
  __shared__ int buf[256];
  const int t = threadIdx.x;
  const int i = blockIdx.x * 256 + t;
  buf[t] = (i < n) ? deg[i] : 0;
  __syncthreads();
  for (int o = 128; o > 0; o >>= 1) {
    if (t < o) buf[t] += buf[t + o];
    __syncthreads();
  }
  if (t == 0) bsum[blockIdx.x] = buf[0];
}

__global__ __launch_bounds__(256) void scan_bsums(int* __restrict__ bsum, int nb) {
  // nb <= 256. In-place exclusive scan.
  __shared__ int buf[256];
  const int t = threadIdx.x;
  int orig = (t < nb) ? bsum[t] : 0;
  buf[t] = orig;
  __syncthreads();
  for (int o = 1; o < 256; o <<= 1) {
    int v = (t >= o) ? buf[t - o] : 0;
    __syncthreads();
    buf[t] += v;
    __syncthreads();
  }
  if (t < nb) bsum[t] = buf[t] - orig;  // exclusive
}

__global__ __launch_bounds__(256) void scan_finalize(const int* __restrict__ deg,
                                                     const int* __restrict__ bsum,
                                                     int* __restrict__ row_start, int n) {
  __shared__ int buf[256];
  const int t = threadIdx.x;
  const int i = blockIdx.x * 256 + t;
  int v = (i < n) ? deg[i] : 0;
  buf[t] = v;
  __syncthreads();
  for (int o = 1; o < 256; o <<= 1) {
    int x = (t >= o) ? buf[t - o] : 0;
    __syncthreads();
    buf[t] += x;
    __syncthreads();
  }
  if (i < n) row_start[i + 1] = bsum[blockIdx.x] + buf[t];
  if (i == 0) row_start[0] = 0;
}

__global__ void scatter_edges(const void* __restrict__ ei, int E,
                              const int* __restrict__ row_start,
                              int* __restrict__ cursor, int* __restrict__ col_src,
                              const int* __restrict__ flags) {
  int e = blockIdx.x * blockDim.x + threadIdx.x;
  if (e >= E) return;
  int s, d;
  if (flags[1]) { s = loadI<true>(ei, e);  d = loadI<true>(ei, (size_t)E + e); }
  else          { s = loadI<false>(ei, e); d = loadI<false>(ei, (size_t)E + e); }
  int pos = atomicAdd(&cursor[d], 1);
  col_src[row_start[d] + pos] = s;
}

// ----------------- aggregation v2 ------------------------------------------
// Block = H waves, one dst per block; wave hh handles head hh.
// Within a wave: lane = (slot = l>>4, el = l&15); lane covers channels
// 4*el..4*el+3 of its head; slot = which of 4 concurrent edges.
// Pass 1: max (64 edges/iter, as round 4). Fused pass 2+3: stage 64 weights
// in LDS (p accumulated in the same strided order as the old pass 2), then
// gather with 4 edges in flight. Epilogue reduces slots via shfl_xor(16/32).
template <int H, bool APPLY_ELU>
__global__ void aggregate_v(const __hip_bfloat16* __restrict__ h_in,
                            const float* __restrict__ as_, const float* __restrict__ ad_,
                            const void* __restrict__ bias,
                            const int* __restrict__ row_start,
                            const int* __restrict__ col_src,
                            void* __restrict__ out,
                            const int* __restrict__ flags, int forceOutBf) {
  __shared__ float w_lds[H][64];
  __shared__ int s_lds[64];
  const int dst = blockIdx.x;
  const int hh = threadIdx.x >> 6;
  const int l = threadIdx.x & 63;
  const int el = l & 15;
  const int slot = l >> 4;
  const bool f = flags[0] != 0;
  const int rs = row_start[dst];
  const int dg = row_start[dst + 1] - rs;
  const float adv = ad_[dst * H + hh];
  const float es = lrelu(as_[dst * H + hh] + adv);

  // pass 1: max over incoming edges
  float m = es;
  for (int base = 0; base < dg; base += 64) {
    int i = base + l;
    if (i < dg) m = fmaxf(m, lrelu(as_[col_src[rs + i] * H + hh] + adv));
  }
#pragma unroll
  for (int o = 32; o > 0; o >>= 1) m = fmaxf(m, __shfl_xor(m, o));

  const float wself = __expf(es - m);

  // fused pass 2+3
  float p = 0.f;
  float a0 = 0.f, a1 = 0.f, a2 = 0.f, a3 = 0.f;
  if (slot == 0) {
    const unsigned short* rp =
        (const unsigned short*)h_in + ((size_t)dst * H + hh) * 64 + 4 * el;
    ushort4 sv = *(const ushort4*)rp;
    a0 = wself * bfbits2f(sv.x);
    a1 = wself * bfbits2f(sv.y);
    a2 = wself * bfbits2f(sv.z);
    a3 = wself * bfbits2f(sv.w);
  }
  for (int base = 0; base < dg; base += 64) {
    int i = base + l;
    if (i < dg) {
      int sn = col_src[rs + i];
      if (hh == 0) s_lds[l] = sn;
      float w = __expf(lrelu(as_[sn * H + hh] + adv) - m);
      w_lds[hh][l] = w;
      p += w;
    }
    __syncthreads();
    const int cnt = min(64, dg - base);
    for (int e = slot; e < cnt; e += 4) {
      int sn = s_lds[e];
      float w = w_lds[hh][e];
      const unsigned short* rp =
          (const unsigned short*)h_in + ((size_t)sn * H + hh) * 64 + 4 * el;
      ushort4 sv = *(const ushort4*)rp;
      a0 += w * bfbits2f(sv.x);
      a1 += w * bfbits2f(sv.y);
      a2 += w * bfbits2f(sv.z);
      a3 += w * bfbits2f(sv.w);
    }
    __syncthreads();
  }
#pragma unroll
  for (int o = 32; o > 0; o >>= 1) p += __shfl_xor(p, o);
  const float inv = 1.0f / (p + wself + 1e-16f);

  a0 += __shfl_xor(a0, 16); a0 += __shfl_xor(a0, 32);
  a1 += __shfl_xor(a1, 16); a1 += __shfl_xor(a1, 32);
  a2 += __shfl_xor(a2, 16); a2 += __shfl_xor(a2, 32);
  a3 += __shfl_xor(a3, 16); a3 += __shfl_xor(a3, 32);

  if (slot == 0) {
    const int cb = hh * 64 + 4 * el;
    float b0, b1, b2, b3;
    if (f) {
      b0 = loadF<true>(bias, cb + 0); b1 = loadF<true>(bias, cb + 1);
      b2 = loadF<true>(bias, cb + 2); b3 = loadF<true>(bias, cb + 3);
    } else {
      b0 = loadF<false>(bias, cb + 0); b1 = loadF<false>(bias, cb + 1);
      b2 = loadF<false>(bias, cb + 2); b3 = loadF<false>(bias, cb + 3);
    }
    float o0 = a0 * inv + b0, o1 = a1 * inv + b1;
    float o2 = a2 * inv + b2, o3 = a3 * inv + b3;
    if (APPLY_ELU) {
      o0 = o0 > 0.f ? o0 : __expf(o0) - 1.f;
      o1 = o1 > 0.f ? o1 : __expf(o1) - 1.f;
      o2 = o2 > 0.f ? o2 : __expf(o2) - 1.f;
      o3 = o3 > 0.f ? o3 : __expf(o3) - 1.f;
    }
    const size_t ob = (size_t)dst * H * 64 + cb;
    if (forceOutBf || f) {
      storeF<true>(out, ob + 0, o0); storeF<true>(out, ob + 1, o1);
      storeF<true>(out, ob + 2, o2); storeF<true>(out, ob + 3, o3);
    } else {
      float4 ov; ov.x = o0; ov.y = o1; ov.z = o2; ov.w = o3;
      *(float4*)((float*)out + ob) = ov;
    }
  }
}

// ----------------- fallback aggregate (round-4 version, dynamic H) ---------
template <bool APPLY_ELU>
__global__ void aggregate(const __hip_bfloat16* __restrict__ h_in,
                          const float* __restrict__ as_, const float* __restrict__ ad_,
                          const void* __restrict__ bias,
                          const int* __restrict__ row_start, const int* __restrict__ col_src,
                          void* __restrict__ out, int H,
                          const int* __restrict__ flags, int forceOutBf) {
  __shared__ float w_lds[4][64];
  __shared__ int s_lds[4][64];
  const int dst = blockIdx.x;
  const int hh = threadIdx.x >> 6;
  const int l = threadIdx.x & 63;
  const bool f = flags[0] != 0;
  const int rs = row_start[dst];
  const int deg = row_start[dst + 1] - rs;
  const float adv = ad_[dst * H + hh];
  float e_self = lrelu(as_[dst * H + hh] + adv);
  float m = e_self;
  for (int base = 0; base < deg; base += 64) {
    int i = base + l;
    if (i < deg) m = fmaxf(m, lrelu(as_[col_src[rs + i] * H + hh] + adv));
  }
#pragma unroll
  for (int o = 32; o > 0; o >>= 1) m = fmaxf(m, __shfl_xor(m, o));
  float p = 0.f;
  for (int base = 0; base < deg; base += 64) {
    int i = base + l;
    if (i < deg) p += __expf(lrelu(as_[col_src[rs + i] * H + hh] + adv) - m);
  }
#pragma unroll
  for (int o = 32; o > 0; o >>= 1) p += __shfl_xor(p, o);
  const float w_self = __expf(e_self - m);
  const float inv = 1.0f / (p + w_self + 1e-16f);
  float acc = w_self * bf2f(h_in[((size_t)dst * H + hh) * 64 + l]);
  for (int base = 0; base < deg; base += 64) {
    int i = base + l;
    if (i < deg) {
      int sn = col_src[rs + i];
      s_lds[hh][l] = sn;
      w_lds[hh][l] = __expf(lrelu(as_[sn * H + hh] + adv) - m);
    }
    __syncthreads();
    const int cnt = min(64, deg - base);
#pragma unroll 4
    for (int e = 0; e < cnt; e++)
      acc += w_lds[hh][e] * bf2f(h_in[((size_t)s_lds[hh][e] * H + hh) * 64 + l]);
    __syncthreads();
  }
  float bv = f ? loadF<true>(bias, hh * 64 + l) : loadF<false>(bias, hh * 64 + l);
  float o = acc * inv + bv;
  if (APPLY_ELU) o = o > 0.f ? o : __expf(o) - 1.0f;
  size_t oi = ((size_t)dst * H + hh) * 64 + l;
  if (forceOutBf || f) storeF<true>(out, oi, o);
  else                 storeF<false>(out, oi, o);
}

// ---------------------------------------------------------------------------
extern "C" void kernel_launch(void* const* d_in, const int* in_sizes, int n_in,
                              void* d_out, int out_size, void* d_ws, size_t ws_size,
                              hipStream_t stream) {
  const void* x    = d_in[0];
  const void* ei   = d_in[1];
  const void* W1   = d_in[2];
  const void* as1w = d_in[3];
  const void* ad1w = d_in[4];
  const void* b1   = d_in[5];
  const void* W2   = d_in[6];
  const void* as2w = d_in[7];
  const void* ad2w = d_in[8];
  const void* b2   = d_in[9];

  const int N  = out_size / 64;      // 50000
  const int F  = in_sizes[0] / N;    // 128
  const int E  = in_sizes[1] / 2;    // 800000
  const int H1 = in_sizes[3] / 64;   // 4
  const int D1 = H1 * 64;            // 256
  const int H2 = in_sizes[7] / 64;   // 1
  const int D2 = H2 * 64;            // 64

  size_t off = 0;
  auto alloc = [&](size_t bytes) -> void* {
    void* p = (char*)d_ws + off;
    off += (bytes + 255) & ~(size_t)255;
    return p;
  };
  int* flags = (int*)alloc(2 * sizeof(int));
  __hip_bfloat16* h1 = (__hip_bfloat16*)alloc((size_t)N * D1 * 2);
  __hip_bfloat16* x2 = (__hip_bfloat16*)alloc((size_t)N * D1 * 2);
  __hip_bfloat16* h2 = h1;  // h1 dead after layer-1 aggregate; reuse
  float* as1 = (float*)alloc((size_t)N * H1 * 4);
  float* ad1 = (float*)alloc((size_t)N * H1 * 4);
  float* as2 = (float*)alloc((size_t)N * H2 * 4);
  float* ad2 = (float*)alloc((size_t)N * H2 * 4);
  int* degcur = (int*)alloc((size_t)2 * N * 4);  // deg | cursor
  int* deg = degcur;
  int* cursor = degcur + N;
  int* row_start = (int*)alloc((size_t)(N + 1) * 4);
  int* col_src = (int*)alloc((size_t)E * 4);
  int* bsum = (int*)alloc((size_t)256 * 4);
  (void)ws_size; (void)n_in;

  const int nb = (N + 255) / 256;  // 196 <= 256

  // ---- dtype detection + CSR build
  detect_kernel<<<1, 64, 0, stream>>>((const uint32_t*)x, (const uint32_t*)ei, flags);
  hipMemsetAsync(degcur, 0, (size_t)2 * N * 4, stream);
  hist_kernel<<<(E + 255) / 256, 256, 0, stream>>>(ei, E, deg, flags);
  scan_block_sums<<<nb, 256, 0, stream>>>(deg, bsum, N);
  scan_bsums<<<1, 256, 0, stream>>>(bsum, nb);
  scan_finalize<<<nb, 256, 0, stream>>>(deg, bsum, row_start, N);
  scatter_edges<<<(E + 255) / 256, 256, 0, stream>>>(ei, E, row_start, cursor, col_src, flags);

  // ---- layer 1
  gemm_any<<<dim3((N + BM - 1) / BM, D1 / BN), 256, 0, stream>>>(x, W1, h1, N, F, D1, flags, 0);
  att_dot<<<N, H1 * 64, 0, stream>>>(h1, as1w, ad1w, as1, ad1, H1, flags);
  if (H1 == 4)
    aggregate_v<4, true><<<N, 256, 0, stream>>>(h1, as1, ad1, b1, row_start, col_src,
                                                x2, flags, 1);
  else
    aggregate<true><<<N, H1 * 64, 0, stream>>>(h1, as1, ad1, b1, row_start, col_src,
                                               x2, H1, flags, 1);

  // ---- layer 2
  gemm_any<<<dim3((N + BM - 1) / BM, D2 / BN), 256, 0, stream>>>(x2, W2, h2, N, D1, D2, flags, 1);
  att_dot<<<N, H2 * 64, 0, stream>>>(h2, as2w, ad2w, as2, ad2, H2, flags);
  if (H2 == 1)
    aggregate_v<1, false><<<N, 64, 0, stream>>>(h2, as2, ad2, b2, row_start, col_src,
                                                d_out, flags, 0);
  else
    aggregate<false><<<N, H2 * 64, 0, stream>>>(h2, as2, ad2, b2, row_start, col_src,
                                                d_out, H2, flags, 0);
}